// Round 21
// baseline (2983.027 us; speedup 1.0000x reference)
//
#include <hip/hip_runtime.h>
#include <hip/hip_bf16.h>

#define T_TOK 8192
#define D_DIM 1024
#define F_DIM 4096
#define E_NUM 8
#define BM 128
#define MAX_ROWS (2 * T_TOK + E_NUM * BM)   // 17408
#define NUM_RB (MAX_ROWS / BM)              // 136
#define G1_BLOCKS (NUM_RB * (F_DIM / 128))  // 4352

typedef __hip_bfloat16 bf16;
using bf16x8  = __attribute__((ext_vector_type(8))) __bf16;
using float4v = __attribute__((ext_vector_type(4))) float;
using f32x4   = __attribute__((ext_vector_type(4))) float;
using u16x4v  = __attribute__((ext_vector_type(4))) unsigned short;

// async global->LDS, 16B per lane; dest = uniform base + lane*16
__device__ inline void gl_lds16(const bf16* g, bf16* l) {
    __builtin_amdgcn_global_load_lds(
        (const __attribute__((address_space(1))) void*)g,
        (__attribute__((address_space(3))) void*)l, 16, 0, 0);
}

// R4 phase: counted vmcnt, pinned reads, 2 barriers, stage after 2nd barrier.
#define PH(WAITSTR, CA, CB, DOSTAGE, KST)                                      \
    do {                                                                       \
        asm volatile("s_waitcnt " WAITSTR ::: "memory");                       \
        __builtin_amdgcn_s_barrier();                                          \
        bf16x8 af[4], bfr[4];                                                  \
        _Pragma("unroll")                                                      \
        for (int m_ = 0; m_ < 4; ++m_)                                         \
            af[m_] = *(const bf16x8*)&(CA)[(wrow + m_ * 16 + fr) * 32 + fkk];  \
        _Pragma("unroll")                                                      \
        for (int n_ = 0; n_ < 4; ++n_)                                         \
            bfr[n_] = *(const bf16x8*)&(CB)[(wcol + n_ * 16 + fr) * 32 + fkk]; \
        asm volatile("s_waitcnt lgkmcnt(0)" ::: "memory");                     \
        __builtin_amdgcn_sched_barrier(0);                                     \
        __builtin_amdgcn_s_barrier();                                          \
        if (DOSTAGE) stage(KST, CA, CB);                                       \
        __builtin_amdgcn_s_setprio(1);                                         \
        _Pragma("unroll")                                                      \
        for (int m_ = 0; m_ < 4; ++m_)                                         \
            _Pragma("unroll")                                                  \
            for (int n_ = 0; n_ < 4; ++n_)                                     \
                acc[m_][n_] = __builtin_amdgcn_mfma_f32_16x16x32_bf16(         \
                    af[m_], bfr[n_], acc[m_][n_], 0, 0, 0);                    \
        __builtin_amdgcn_s_setprio(0);                                         \
    } while (0)

// shared transpose tile body (64x64 f32 -> bf16^T)
__device__ inline void transpose_tile(const float* s, bf16* d, int N, int M,
                                      int n0, int m0, float (*tile)[65]) {
    const int tx = threadIdx.x & 15, ty = threadIdx.x >> 4;
#pragma unroll
    for (int i = 0; i < 4; ++i) {
        const int r = ty + i * 16;
        const f32x4 v = *(const f32x4*)&s[(size_t)(m0 + r) * N + n0 + tx * 4];
        tile[r][tx * 4 + 0] = v[0];
        tile[r][tx * 4 + 1] = v[1];
        tile[r][tx * 4 + 2] = v[2];
        tile[r][tx * 4 + 3] = v[3];
    }
    __syncthreads();
#pragma unroll
    for (int i = 0; i < 4; ++i) {
        const int nc = ty + i * 16;
        u16x4v ov;
#pragma unroll
        for (int j = 0; j < 4; ++j) {
            bf16 b = __float2bfloat16(tile[tx * 4 + j][nc]);
            ov[j] = *(unsigned short*)&b;
        }
        *(u16x4v*)&d[(size_t)(n0 + nc) * M + m0 + tx * 4] = ov;
    }
}

// ---- fat dispatch A: W1-transpose (blocks 0..8191) + router+xcvt ----
__global__ __launch_bounds__(256) void prepA_kernel(
    const float* __restrict__ W1, bf16* __restrict__ W1t,
    const float* __restrict__ x, const float* __restrict__ Wg,
    const float* __restrict__ bg, int* __restrict__ top_idx,
    float* __restrict__ top_gate, bf16* __restrict__ xb) {
    __shared__ alignas(16) char pool[16640];
    const int bid = blockIdx.x;
    if (bid < 8192) {
        const int e = bid >> 10, rem = bid & 1023;
        const int n0 = (rem & 63) * 64, m0 = (rem >> 6) * 64;   // N=F, M=D
        transpose_tile(W1 + (size_t)e * D_DIM * F_DIM,
                       W1t + (size_t)e * D_DIM * F_DIM,
                       F_DIM, D_DIM, n0, m0, (float(*)[65])pool);
        return;
    }
    const int rbid = bid - 8192;
    const int lane = threadIdx.x & 63;
    const int t = rbid * 4 + (threadIdx.x >> 6);
    const float* xrow = x + (size_t)t * D_DIM;

    float acc[E_NUM];
#pragma unroll
    for (int e = 0; e < E_NUM; ++e) acc[e] = 0.f;
#pragma unroll
    for (int it = 0; it < D_DIM / 64; ++it) {
        const int d = it * 64 + lane;
        const float xv = xrow[d];
        const float4 w0 = *(const float4*)&Wg[d * 8];
        const float4 w1 = *(const float4*)&Wg[d * 8 + 4];
        acc[0] += xv * w0.x; acc[1] += xv * w0.y;
        acc[2] += xv * w0.z; acc[3] += xv * w0.w;
        acc[4] += xv * w1.x; acc[5] += xv * w1.y;
        acc[6] += xv * w1.z; acc[7] += xv * w1.w;
    }
#pragma unroll
    for (int off = 32; off > 0; off >>= 1) {
#pragma unroll
        for (int e = 0; e < E_NUM; ++e) acc[e] += __shfl_xor(acc[e], off, 64);
    }
    if (lane == 0) {
        float v[E_NUM];
#pragma unroll
        for (int e = 0; e < E_NUM; ++e) v[e] = acc[e] + bg[e];
        int i0 = 0;
#pragma unroll
        for (int e = 1; e < E_NUM; ++e)
            if (v[e] > v[i0]) i0 = e;
        int i1 = -1;
#pragma unroll
        for (int e = 0; e < E_NUM; ++e) {
            if (e == i0) continue;
            if (i1 < 0 || v[e] > v[i1]) i1 = e;
        }
        const float g0 = 1.f / (1.f + expf(v[i1] - v[i0]));
        top_idx[2 * t] = i0;
        top_idx[2 * t + 1] = i1;
        top_gate[2 * t] = g0;
        top_gate[2 * t + 1] = 1.f - g0;
    }
    const float4* xs = (const float4*)(x + (size_t)rbid * 4 * D_DIM);
    ushort4* xd = (ushort4*)(xb + (size_t)rbid * 4 * D_DIM);
    for (int i = threadIdx.x; i < D_DIM; i += 256) {
        float4 v = xs[i];
        bf16 tmp[4];
        tmp[0] = __float2bfloat16(v.x);
        tmp[1] = __float2bfloat16(v.y);
        tmp[2] = __float2bfloat16(v.z);
        tmp[3] = __float2bfloat16(v.w);
        xd[i] = *(const ushort4*)tmp;
    }
}

// ---- scatter with inline recount+offsets ----
__global__ __launch_bounds__(256) void scatter_kernel(
    const int* __restrict__ top_idx, const float* __restrict__ top_gate,
    int* __restrict__ offsets, int* __restrict__ cursors,
    int* __restrict__ tok_list, float* __restrict__ gate_list,
    int* __restrict__ tok_slots) {
    __shared__ int whist[4][E_NUM];
    __shared__ int offs_s[E_NUM + 1];
    __shared__ int lhist[E_NUM];
    __shared__ int lbase[E_NUM];

    int cnt[E_NUM];
#pragma unroll
    for (int e = 0; e < E_NUM; ++e) cnt[e] = 0;
    for (int i = threadIdx.x; i < 2 * T_TOK; i += 256) {
        const int idx = top_idx[i];
#pragma unroll
        for (int e = 0; e < E_NUM; ++e) cnt[e] += (idx == e) ? 1 : 0;
    }
#pragma unroll
    for (int off = 32; off > 0; off >>= 1) {
#pragma unroll
        for (int e = 0; e < E_NUM; ++e) cnt[e] += __shfl_xor(cnt[e], off, 64);
    }
    const int lane = threadIdx.x & 63, w = threadIdx.x >> 6;
    if (lane == 0) {
#pragma unroll
        for (int e = 0; e < E_NUM; ++e) whist[w][e] = cnt[e];
    }
    if (threadIdx.x < E_NUM) lhist[threadIdx.x] = 0;
    __syncthreads();
    if (threadIdx.x == 0) {
        int o = 0;
#pragma unroll
        for (int e = 0; e < E_NUM; ++e) {
            const int c = whist[0][e] + whist[1][e] + whist[2][e] + whist[3][e];
            offs_s[e] = o;
            o += (c + BM - 1) / BM * BM;
        }
        offs_s[E_NUM] = o;
    }
    __syncthreads();
    if (blockIdx.x == 0 && threadIdx.x < E_NUM + 1)
        offsets[threadIdx.x] = offs_s[threadIdx.x];

    const int t = blockIdx.x * 256 + threadIdx.x;
    int e0 = top_idx[2 * t], e1 = top_idx[2 * t + 1];
    int p0 = atomicAdd(&lhist[e0], 1);
    int p1 = atomicAdd(&lhist[e1], 1);
    __syncthreads();
    if (threadIdx.x < E_NUM)
        lbase[threadIdx.x] = atomicAdd(&cursors[threadIdx.x], lhist[threadIdx.x]);
    __syncthreads();

    const float g0 = top_gate[2 * t], g1 = top_gate[2 * t + 1];
    const int s0 = offs_s[e0] + lbase[e0] + p0;
    const int s1 = offs_s[e1] + lbase[e1] + p1;
    tok_list[s0] = t;
    gate_list[s0] = g0;
    tok_list[s1] = t;
    gate_list[s1] = g1;
    tok_slots[2 * t] = s0;
    tok_slots[2 * t + 1] = s1;
}

// ---- fat dispatch B: GEMM1 (exact R4, LDS=32KB -> 5 blocks/CU) + W2-T ----
__global__ __launch_bounds__(256, 5) void gemm1_w2t_kernel(
    const bf16* __restrict__ xb, const bf16* __restrict__ W1t,
    const float* __restrict__ b1, const int* __restrict__ tok_list,
    const int* __restrict__ offsets, bf16* __restrict__ hbuf,
    const float* __restrict__ W2, bf16* __restrict__ W2t) {
    __shared__ alignas(16) char pool[32768];
    if (blockIdx.x >= G1_BLOCKS) {
        const int f2 = blockIdx.x - G1_BLOCKS;
        const int e = f2 >> 10, rem = f2 & 1023;
        const int n0 = (rem & 15) * 64, m0 = (rem >> 4) * 64;   // N=D, M=F
        transpose_tile(W2 + (size_t)e * D_DIM * F_DIM,
                       W2t + (size_t)e * D_DIM * F_DIM,
                       D_DIM, F_DIM, n0, m0, (float(*)[65])pool);
        return;
    }
    bf16* As0 = (bf16*)pool;
    bf16* As1 = (bf16*)(pool + 8192);
    bf16* Bs0 = (bf16*)(pool + 16384);
    bf16* Bs1 = (bf16*)(pool + 24576);

    const int NCB = F_DIM / 128;          // 32
    const int per = (NUM_RB * NCB) / 8;   // 544
    const int flat = blockIdx.x;
    const int sw = (flat & 7) * per + (flat >> 3);
    const int rb = sw / NCB, cb = sw % NCB;

    const int row0 = rb * BM;
    const int total = offsets[E_NUM];
    if (row0 >= total) return;
    int e = 0;
#pragma unroll
    for (int i = 1; i < E_NUM; ++i) e += (row0 >= offsets[i]) ? 1 : 0;

    const int tid = threadIdx.x;
    const int lane = tid & 63;
    const int w = tid >> 6;
    const int f0 = cb * 128;

    // per-thread direct tok reads (drained before stage(0) via addr data-dep)
    const int r0 = w * 16 + (lane >> 2);
    const int r1 = 64 + w * 16 + (lane >> 2);
    const int c16 = (lane & 3) ^ ((lane >> 3) & 3);
    int t0 = tok_list[row0 + r0]; if (t0 < 0) t0 = 0;
    int t1 = tok_list[row0 + r1]; if (t1 < 0) t1 = 0;
    const bf16* aP0 = xb + (size_t)t0 * D_DIM + c16 * 8;
    const bf16* aP1 = xb + (size_t)t1 * D_DIM + c16 * 8;
    const bf16* bP0 = W1t + ((size_t)e * F_DIM + f0 + r0) * D_DIM + c16 * 8;
    const bf16* bP1 = W1t + ((size_t)e * F_DIM + f0 + r1) * D_DIM + c16 * 8;

    const unsigned dO0 = __builtin_amdgcn_readfirstlane(w * 1024);
    const unsigned dO1 = __builtin_amdgcn_readfirstlane(4096 + w * 1024);

    const int wrow = (w >> 1) * 64, wcol = (w & 1) * 64;
    const int fr = lane & 15;
    const int fkk = 8 * ((lane >> 4) ^ ((lane >> 1) & 3));

    float4v acc[4][4];
#pragma unroll
    for (int m = 0; m < 4; ++m)
#pragma unroll
        for (int n = 0; n < 4; ++n)
#pragma unroll
            for (int r = 0; r < 4; ++r) acc[m][n][r] = 0.f;

    auto stage = [&](int kt, bf16* A, bf16* B) {
        const int ko = kt * 32;
        gl_lds16(aP0 + ko, (bf16*)((char*)A + dO0));
        gl_lds16(aP1 + ko, (bf16*)((char*)A + dO1));
        gl_lds16(bP0 + ko, (bf16*)((char*)B + dO0));
        gl_lds16(bP1 + ko, (bf16*)((char*)B + dO1));
    };

    const int NKT = D_DIM / 32;  // 32
    stage(0, As0, Bs0);
    stage(1, As1, Bs1);
    for (int kt = 0; kt < NKT - 2; kt += 2) {
        PH("vmcnt(4)", As0, Bs0, true, kt + 2);
        PH("vmcnt(4)", As1, Bs1, true, kt + 3);
    }
    PH("vmcnt(4)", As0, Bs0, false, 0);
    PH("vmcnt(0)", As1, Bs1, false, 0);

#pragma unroll
    for (int n = 0; n < 4; ++n) {
        const int gcol = f0 + wcol + n * 16 + fr;
        const float bias = b1[e * F_DIM + gcol];
#pragma unroll
        for (int m = 0; m < 4; ++m) {
#pragma unroll
            for (int r = 0; r < 4; ++r) {
                const int grow = row0 + wrow + m * 16 + (lane >> 4) * 4 + r;
                float v = acc[m][n][r] + bias;
                v = fmaxf(v, 0.f);
                hbuf[(size_t)grow * F_DIM + gcol] = __float2bfloat16(v);
            }
        }
    }
}

// ---------------- GEMM2 (exact R4 loop, LDS=32KB -> 5 blocks/CU) ------------
// y[slot] = gate*(h@W2 + b2) via plain stores; gate read direct in epilogue.
__global__ __launch_bounds__(256, 5) void gemm2_kernel(
    const bf16* __restrict__ hbuf, const bf16* __restrict__ W2t,
    const float* __restrict__ b2, const float* __restrict__ gate_list,
    const int* __restrict__ offsets, bf16* __restrict__ y) {
    __shared__ bf16 As0[BM * 32];
    __shared__ bf16 As1[BM * 32];
    __shared__ bf16 Bs0[BM * 32];
    __shared__ bf16 Bs1[BM * 32];

    const int NCB = D_DIM / 128;          // 8
    const int per = (NUM_RB * NCB) / 8;   // 136
    const int flat = blockIdx.x;
    const int sw = (flat & 7) * per + (flat >> 3);
    const int rb = sw / NCB, cb = sw % NCB;

    const int row0 = rb * BM;
    const int total = offsets[E_NUM];
    if (row0 >= total) return;
    int e = 0;
#pragma unroll
    for (int i = 1; i < E_NUM; ++i) e += (row0 >= offsets[i]) ? 1 : 0;

    const int tid = threadIdx.x;
    const int lane = tid & 63;
    const int w = tid >> 6;
    const int d0 = cb * 128;

    const int r0 = w * 16 + (lane >> 2);
    const int r1 = 64 + w * 16 + (lane >> 2);
    const int c16 = (lane & 3) ^ ((lane >> 3) & 3);
    const bf16* aP0 = hbuf + (size_t)(row0 + r0) * F_DIM + c16 * 8;
    const bf16* aP1 = hbuf + (size_t)(row0 + r1) * F_DIM + c16 * 8;
    const bf16* bP0 = W2t + ((size_t)e * D_DIM + d0 + r0) * F_DIM + c16 * 8;
    const bf16* bP1 = W2t + ((size_t)e * D_DIM + d0 + r1) * F_DIM + c16 * 8;

    const unsigned dO0 = __builtin_amdgcn_readfirstlane(w * 1024);
    const unsigned dO1 = __builtin_amdgcn_readfirstlane(4096 + w * 1024);

    const int wrow = (w >> 1) * 64, wcol = (w & 1) * 64;
    const int fr = lane & 15;
    const int fkk = 8 * ((lane >> 4) ^ ((lane >> 1) & 3));

    float4v acc[4][4];
#pragma unroll
    for (int m = 0; m < 4; ++m)
#pragma unroll
        for (int n = 0; n < 4; ++n)
#pragma unroll
            for (int r = 0; r < 4; ++r) acc[m][n][r] = 0.f;

    auto stage = [&](int kt, bf16* A, bf16* B) {
        const int ko = kt * 32;
        gl_lds16(aP0 + ko, (bf16*)((char*)A + dO0));
        gl_lds16(aP1 + ko, (bf16*)((char*)A + dO1));
        gl_lds16(bP0 + ko, (bf16*)((char*)B + dO0));
        gl_lds16(bP1 + ko, (bf16*)((char*)B + dO1));
    };

    const int NKT = F_DIM / 32;  // 128
    stage(0, As0, Bs0);
    stage(1, As1, Bs1);
    for (int kt = 0; kt < NKT - 2; kt += 2) {
        PH("vmcnt(4)", As0, Bs0, true, kt + 2);
        PH("vmcnt(4)", As1, Bs1, true, kt + 3);
    }
    PH("vmcnt(4)", As0, Bs0, false, 0);
    PH("vmcnt(0)", As1, Bs1, false, 0);

#pragma unroll
    for (int n = 0; n < 4; ++n) {
        const int gcol = d0 + wcol + n * 16 + fr;
        const float bias = b2[e * D_DIM + gcol];
#pragma unroll
        for (int m = 0; m < 4; ++m) {
#pragma unroll
            for (int r = 0; r < 4; ++r) {
                const int lrow = wrow + m * 16 + (lane >> 4) * 4 + r;
                const float g = gate_list[row0 + lrow];   // L2-hot, 128/block
                const float v = (acc[m][n][r] + bias) * g;
                y[(size_t)(row0 + lrow) * D_DIM + gcol] = __float2bfloat16(v);
            }
        }
    }
}

// ---- final reduce: out[t] = y[slot0(t)] + y[slot1(t)] (bf16 in, f32 out) ----
__global__ __launch_bounds__(256) void reduce_kernel(
    const bf16* __restrict__ y, const int* __restrict__ tok_slots,
    float* __restrict__ out) {
    const int t = blockIdx.x;
    const int s0 = tok_slots[2 * t], s1 = tok_slots[2 * t + 1];
    const ushort4* y0 = (const ushort4*)(y + (size_t)s0 * D_DIM);
    const ushort4* y1 = (const ushort4*)(y + (size_t)s1 * D_DIM);
    float4* o = (float4*)(out + (size_t)t * D_DIM);
    const int i = threadIdx.x;           // 256 threads x 4 bf16 = 1024 ✓
    const ushort4 a = y0[i], b = y1[i];
    const bf16* ap = (const bf16*)&a;
    const bf16* bp = (const bf16*)&b;
    float4 r;
    r.x = __bfloat162float(ap[0]) + __bfloat162float(bp[0]);
    r.y = __bfloat162float(ap[1]) + __bfloat162float(bp[1]);
    r.z = __bfloat162float(ap[2]) + __bfloat162float(bp[2]);
    r.w = __bfloat162float(ap[3]) + __bfloat162float(bp[3]);
    o[i] = r;
}

extern "C" void kernel_launch(void* const* d_in, const int* in_sizes, int n_in,
                              void* d_out, int out_size, void* d_ws, size_t ws_size,
                              hipStream_t stream) {
    const float* x = (const float*)d_in[0];
    const float* Wg = (const float*)d_in[1];
    const float* bg = (const float*)d_in[2];
    const float* W1 = (const float*)d_in[3];
    const float* b1 = (const float*)d_in[4];
    const float* W2 = (const float*)d_in[5];
    const float* b2 = (const float*)d_in[6];
    float* out = (float*)d_out;

    char* ws = (char*)d_ws;
    int* cursors = (int*)(ws + 32);     // 8 ints
    int* offsets = (int*)(ws + 64);     // 9 ints
    int* top_idx = (int*)(ws + 256);                     // T*2 ints
    float* top_gate = (float*)(ws + 256 + 65536);        // T*2 floats
    int* tok_list = (int*)(ws + 256 + 2 * 65536);        // MAX_ROWS ints
    float* gate_list = (float*)(ws + 256 + 2 * 65536 + 69632);
    int* tok_slots = (int*)(ws + 270592);                // T*2 ints = 64 KB
    size_t off = 270592 + 65536;                          // 336128
    bf16* xb = (bf16*)(ws + off);                        // 16.8 MB
    bf16* y = (bf16*)(ws + off);                         // 35 MB, aliases xb+W1t
    off += (size_t)T_TOK * D_DIM * 2;                    //  (dead after gemm1)
    bf16* W1t = (bf16*)(ws + off);
    off += (size_t)E_NUM * D_DIM * F_DIM * 2;
    bf16* W2t = (bf16*)(ws + off);
    off += (size_t)E_NUM * D_DIM * F_DIM * 2;
    bf16* hbuf = (bf16*)(ws + off);

    hipMemsetAsync(ws, 0, 64, stream);                       // cursors (+pad)
    hipMemsetAsync(tok_list, 0xFF, (size_t)MAX_ROWS * 4, stream);  // -1 sentinels

    prepA_kernel<<<8192 + T_TOK / 4, 256, 0, stream>>>(W1, W1t, x, Wg, bg,
                                                       top_idx, top_gate, xb);
    scatter_kernel<<<T_TOK / 256, 256, 0, stream>>>(top_idx, top_gate, offsets, cursors,
                                                    tok_list, gate_list, tok_slots);
    gemm1_w2t_kernel<<<G1_BLOCKS + 8192, 256, 0, stream>>>(xb, W1t, b1, tok_list,
                                                           offsets, hbuf, W2, W2t);
    gemm2_kernel<<<NUM_RB * (D_DIM / 128), 256, 0, stream>>>(hbuf, W2t, b2,
                                                             gate_list, offsets, y);
    reduce_kernel<<<T_TOK, 256, 0, stream>>>(y, tok_slots, out);
}

// Round 22
// 526.191 us; speedup vs baseline: 5.6691x; 5.6691x over previous
//
#include <hip/hip_runtime.h>
#include <hip/hip_bf16.h>

#define T_TOK 8192
#define D_DIM 1024
#define F_DIM 4096
#define E_NUM 8
#define BM 128
#define MAX_ROWS (2 * T_TOK + E_NUM * BM)   // 17408
#define NUM_RB (MAX_ROWS / BM)              // 136
#define G1_BLOCKS (NUM_RB * (F_DIM / 128))  // 4352

typedef __hip_bfloat16 bf16;
using bf16x8  = __attribute__((ext_vector_type(8))) __bf16;
using float4v = __attribute__((ext_vector_type(4))) float;
using f32x4   = __attribute__((ext_vector_type(4))) float;
using u16x4v  = __attribute__((ext_vector_type(4))) unsigned short;

// async global->LDS, 16B per lane; dest = uniform base + lane*16
__device__ inline void gl_lds16(const bf16* g, bf16* l) {
    __builtin_amdgcn_global_load_lds(
        (const __attribute__((address_space(1))) void*)g,
        (__attribute__((address_space(3))) void*)l, 16, 0, 0);
}

// R4 phase: counted vmcnt, pinned reads, 2 barriers, stage after 2nd barrier.
#define PH(WAITSTR, CA, CB, DOSTAGE, KST)                                      \
    do {                                                                       \
        asm volatile("s_waitcnt " WAITSTR ::: "memory");                       \
        __builtin_amdgcn_s_barrier();                                          \
        bf16x8 af[4], bfr[4];                                                  \
        _Pragma("unroll")                                                      \
        for (int m_ = 0; m_ < 4; ++m_)                                         \
            af[m_] = *(const bf16x8*)&(CA)[(wrow + m_ * 16 + fr) * 32 + fkk];  \
        _Pragma("unroll")                                                      \
        for (int n_ = 0; n_ < 4; ++n_)                                         \
            bfr[n_] = *(const bf16x8*)&(CB)[(wcol + n_ * 16 + fr) * 32 + fkk]; \
        asm volatile("s_waitcnt lgkmcnt(0)" ::: "memory");                     \
        __builtin_amdgcn_sched_barrier(0);                                     \
        __builtin_amdgcn_s_barrier();                                          \
        if (DOSTAGE) stage(KST, CA, CB);                                       \
        __builtin_amdgcn_s_setprio(1);                                         \
        _Pragma("unroll")                                                      \
        for (int m_ = 0; m_ < 4; ++m_)                                         \
            _Pragma("unroll")                                                  \
            for (int n_ = 0; n_ < 4; ++n_)                                     \
                acc[m_][n_] = __builtin_amdgcn_mfma_f32_16x16x32_bf16(         \
                    af[m_], bfr[n_], acc[m_][n_], 0, 0, 0);                    \
        __builtin_amdgcn_s_setprio(0);                                         \
    } while (0)

// shared transpose tile body (64x64 f32 -> bf16^T)
__device__ inline void transpose_tile(const float* s, bf16* d, int N, int M,
                                      int n0, int m0, float (*tile)[65]) {
    const int tx = threadIdx.x & 15, ty = threadIdx.x >> 4;
#pragma unroll
    for (int i = 0; i < 4; ++i) {
        const int r = ty + i * 16;
        const f32x4 v = *(const f32x4*)&s[(size_t)(m0 + r) * N + n0 + tx * 4];
        tile[r][tx * 4 + 0] = v[0];
        tile[r][tx * 4 + 1] = v[1];
        tile[r][tx * 4 + 2] = v[2];
        tile[r][tx * 4 + 3] = v[3];
    }
    __syncthreads();
#pragma unroll
    for (int i = 0; i < 4; ++i) {
        const int nc = ty + i * 16;
        u16x4v ov;
#pragma unroll
        for (int j = 0; j < 4; ++j) {
            bf16 b = __float2bfloat16(tile[tx * 4 + j][nc]);
            ov[j] = *(unsigned short*)&b;
        }
        *(u16x4v*)&d[(size_t)(n0 + nc) * M + m0 + tx * 4] = ov;
    }
}

// ---- fat dispatch A: W1-transpose (blocks 0..8191) + router+xcvt ----
__global__ __launch_bounds__(256) void prepA_kernel(
    const float* __restrict__ W1, bf16* __restrict__ W1t,
    const float* __restrict__ x, const float* __restrict__ Wg,
    const float* __restrict__ bg, int* __restrict__ top_idx,
    float* __restrict__ top_gate, bf16* __restrict__ xb) {
    __shared__ alignas(16) char pool[16640];
    const int bid = blockIdx.x;
    if (bid < 8192) {
        const int e = bid >> 10, rem = bid & 1023;
        const int n0 = (rem & 63) * 64, m0 = (rem >> 6) * 64;   // N=F, M=D
        transpose_tile(W1 + (size_t)e * D_DIM * F_DIM,
                       W1t + (size_t)e * D_DIM * F_DIM,
                       F_DIM, D_DIM, n0, m0, (float(*)[65])pool);
        return;
    }
    const int rbid = bid - 8192;
    const int lane = threadIdx.x & 63;
    const int t = rbid * 4 + (threadIdx.x >> 6);
    const float* xrow = x + (size_t)t * D_DIM;

    float acc[E_NUM];
#pragma unroll
    for (int e = 0; e < E_NUM; ++e) acc[e] = 0.f;
#pragma unroll
    for (int it = 0; it < D_DIM / 64; ++it) {
        const int d = it * 64 + lane;
        const float xv = xrow[d];
        const float4 w0 = *(const float4*)&Wg[d * 8];
        const float4 w1 = *(const float4*)&Wg[d * 8 + 4];
        acc[0] += xv * w0.x; acc[1] += xv * w0.y;
        acc[2] += xv * w0.z; acc[3] += xv * w0.w;
        acc[4] += xv * w1.x; acc[5] += xv * w1.y;
        acc[6] += xv * w1.z; acc[7] += xv * w1.w;
    }
#pragma unroll
    for (int off = 32; off > 0; off >>= 1) {
#pragma unroll
        for (int e = 0; e < E_NUM; ++e) acc[e] += __shfl_xor(acc[e], off, 64);
    }
    if (lane == 0) {
        float v[E_NUM];
#pragma unroll
        for (int e = 0; e < E_NUM; ++e) v[e] = acc[e] + bg[e];
        int i0 = 0;
#pragma unroll
        for (int e = 1; e < E_NUM; ++e)
            if (v[e] > v[i0]) i0 = e;
        int i1 = -1;
#pragma unroll
        for (int e = 0; e < E_NUM; ++e) {
            if (e == i0) continue;
            if (i1 < 0 || v[e] > v[i1]) i1 = e;
        }
        const float g0 = 1.f / (1.f + expf(v[i1] - v[i0]));
        top_idx[2 * t] = i0;
        top_idx[2 * t + 1] = i1;
        top_gate[2 * t] = g0;
        top_gate[2 * t + 1] = 1.f - g0;
    }
    const float4* xs = (const float4*)(x + (size_t)rbid * 4 * D_DIM);
    ushort4* xd = (ushort4*)(xb + (size_t)rbid * 4 * D_DIM);
    for (int i = threadIdx.x; i < D_DIM; i += 256) {
        float4 v = xs[i];
        bf16 tmp[4];
        tmp[0] = __float2bfloat16(v.x);
        tmp[1] = __float2bfloat16(v.y);
        tmp[2] = __float2bfloat16(v.z);
        tmp[3] = __float2bfloat16(v.w);
        xd[i] = *(const ushort4*)tmp;
    }
}

// ---- scatter with inline recount+offsets ----
__global__ __launch_bounds__(256) void scatter_kernel(
    const int* __restrict__ top_idx, const float* __restrict__ top_gate,
    int* __restrict__ offsets, int* __restrict__ cursors,
    int* __restrict__ tok_list, float* __restrict__ gate_list,
    int* __restrict__ tok_slots) {
    __shared__ int whist[4][E_NUM];
    __shared__ int offs_s[E_NUM + 1];
    __shared__ int lhist[E_NUM];
    __shared__ int lbase[E_NUM];

    int cnt[E_NUM];
#pragma unroll
    for (int e = 0; e < E_NUM; ++e) cnt[e] = 0;
    for (int i = threadIdx.x; i < 2 * T_TOK; i += 256) {
        const int idx = top_idx[i];
#pragma unroll
        for (int e = 0; e < E_NUM; ++e) cnt[e] += (idx == e) ? 1 : 0;
    }
#pragma unroll
    for (int off = 32; off > 0; off >>= 1) {
#pragma unroll
        for (int e = 0; e < E_NUM; ++e) cnt[e] += __shfl_xor(cnt[e], off, 64);
    }
    const int lane = threadIdx.x & 63, w = threadIdx.x >> 6;
    if (lane == 0) {
#pragma unroll
        for (int e = 0; e < E_NUM; ++e) whist[w][e] = cnt[e];
    }
    if (threadIdx.x < E_NUM) lhist[threadIdx.x] = 0;
    __syncthreads();
    if (threadIdx.x == 0) {
        int o = 0;
#pragma unroll
        for (int e = 0; e < E_NUM; ++e) {
            const int c = whist[0][e] + whist[1][e] + whist[2][e] + whist[3][e];
            offs_s[e] = o;
            o += (c + BM - 1) / BM * BM;
        }
        offs_s[E_NUM] = o;
    }
    __syncthreads();
    if (blockIdx.x == 0 && threadIdx.x < E_NUM + 1)
        offsets[threadIdx.x] = offs_s[threadIdx.x];

    const int t = blockIdx.x * 256 + threadIdx.x;
    int e0 = top_idx[2 * t], e1 = top_idx[2 * t + 1];
    int p0 = atomicAdd(&lhist[e0], 1);
    int p1 = atomicAdd(&lhist[e1], 1);
    __syncthreads();
    if (threadIdx.x < E_NUM)
        lbase[threadIdx.x] = atomicAdd(&cursors[threadIdx.x], lhist[threadIdx.x]);
    __syncthreads();

    const float g0 = top_gate[2 * t], g1 = top_gate[2 * t + 1];
    const int s0 = offs_s[e0] + lbase[e0] + p0;
    const int s1 = offs_s[e1] + lbase[e1] + p1;
    tok_list[s0] = t;
    gate_list[s0] = g0;
    tok_list[s1] = t;
    gate_list[s1] = g1;
    tok_slots[2 * t] = s0;
    tok_slots[2 * t + 1] = s1;
}

// ---- fat dispatch B: GEMM1 (exact R4 codegen, LDS=32KB -> 5 blocks/CU via
// LDS limit; launch_bounds stays (256,4) so the allocator keeps 64 VGPRs,
// NO spill) + W2-transpose ----
__global__ __launch_bounds__(256, 4) void gemm1_w2t_kernel(
    const bf16* __restrict__ xb, const bf16* __restrict__ W1t,
    const float* __restrict__ b1, const int* __restrict__ tok_list,
    const int* __restrict__ offsets, bf16* __restrict__ hbuf,
    const float* __restrict__ W2, bf16* __restrict__ W2t) {
    __shared__ alignas(16) char pool[32768];
    if (blockIdx.x >= G1_BLOCKS) {
        const int f2 = blockIdx.x - G1_BLOCKS;
        const int e = f2 >> 10, rem = f2 & 1023;
        const int n0 = (rem & 15) * 64, m0 = (rem >> 4) * 64;   // N=D, M=F
        transpose_tile(W2 + (size_t)e * D_DIM * F_DIM,
                       W2t + (size_t)e * D_DIM * F_DIM,
                       D_DIM, F_DIM, n0, m0, (float(*)[65])pool);
        return;
    }
    bf16* As0 = (bf16*)pool;
    bf16* As1 = (bf16*)(pool + 8192);
    bf16* Bs0 = (bf16*)(pool + 16384);
    bf16* Bs1 = (bf16*)(pool + 24576);

    const int NCB = F_DIM / 128;          // 32
    const int per = (NUM_RB * NCB) / 8;   // 544
    const int flat = blockIdx.x;
    const int sw = (flat & 7) * per + (flat >> 3);
    const int rb = sw / NCB, cb = sw % NCB;

    const int row0 = rb * BM;
    const int total = offsets[E_NUM];
    if (row0 >= total) return;
    int e = 0;
#pragma unroll
    for (int i = 1; i < E_NUM; ++i) e += (row0 >= offsets[i]) ? 1 : 0;

    const int tid = threadIdx.x;
    const int lane = tid & 63;
    const int w = tid >> 6;
    const int f0 = cb * 128;

    // per-thread direct tok reads (drained before stage(0) via addr data-dep)
    const int r0 = w * 16 + (lane >> 2);
    const int r1 = 64 + w * 16 + (lane >> 2);
    const int c16 = (lane & 3) ^ ((lane >> 3) & 3);
    int t0 = tok_list[row0 + r0]; if (t0 < 0) t0 = 0;
    int t1 = tok_list[row0 + r1]; if (t1 < 0) t1 = 0;
    const bf16* aP0 = xb + (size_t)t0 * D_DIM + c16 * 8;
    const bf16* aP1 = xb + (size_t)t1 * D_DIM + c16 * 8;
    const bf16* bP0 = W1t + ((size_t)e * F_DIM + f0 + r0) * D_DIM + c16 * 8;
    const bf16* bP1 = W1t + ((size_t)e * F_DIM + f0 + r1) * D_DIM + c16 * 8;

    const unsigned dO0 = __builtin_amdgcn_readfirstlane(w * 1024);
    const unsigned dO1 = __builtin_amdgcn_readfirstlane(4096 + w * 1024);

    const int wrow = (w >> 1) * 64, wcol = (w & 1) * 64;
    const int fr = lane & 15;
    const int fkk = 8 * ((lane >> 4) ^ ((lane >> 1) & 3));

    float4v acc[4][4];
#pragma unroll
    for (int m = 0; m < 4; ++m)
#pragma unroll
        for (int n = 0; n < 4; ++n)
#pragma unroll
            for (int r = 0; r < 4; ++r) acc[m][n][r] = 0.f;

    auto stage = [&](int kt, bf16* A, bf16* B) {
        const int ko = kt * 32;
        gl_lds16(aP0 + ko, (bf16*)((char*)A + dO0));
        gl_lds16(aP1 + ko, (bf16*)((char*)A + dO1));
        gl_lds16(bP0 + ko, (bf16*)((char*)B + dO0));
        gl_lds16(bP1 + ko, (bf16*)((char*)B + dO1));
    };

    const int NKT = D_DIM / 32;  // 32
    stage(0, As0, Bs0);
    stage(1, As1, Bs1);
    for (int kt = 0; kt < NKT - 2; kt += 2) {
        PH("vmcnt(4)", As0, Bs0, true, kt + 2);
        PH("vmcnt(4)", As1, Bs1, true, kt + 3);
    }
    PH("vmcnt(4)", As0, Bs0, false, 0);
    PH("vmcnt(0)", As1, Bs1, false, 0);

#pragma unroll
    for (int n = 0; n < 4; ++n) {
        const int gcol = f0 + wcol + n * 16 + fr;
        const float bias = b1[e * F_DIM + gcol];
#pragma unroll
        for (int m = 0; m < 4; ++m) {
#pragma unroll
            for (int r = 0; r < 4; ++r) {
                const int grow = row0 + wrow + m * 16 + (lane >> 4) * 4 + r;
                float v = acc[m][n][r] + bias;
                v = fmaxf(v, 0.f);
                hbuf[(size_t)grow * F_DIM + gcol] = __float2bfloat16(v);
            }
        }
    }
}

// ---------------- GEMM2 (exact R4 loop, LDS=32KB, launch_bounds (256,4)) ----
__global__ __launch_bounds__(256, 4) void gemm2_kernel(
    const bf16* __restrict__ hbuf, const bf16* __restrict__ W2t,
    const float* __restrict__ b2, const float* __restrict__ gate_list,
    const int* __restrict__ offsets, bf16* __restrict__ y) {
    __shared__ bf16 As0[BM * 32];
    __shared__ bf16 As1[BM * 32];
    __shared__ bf16 Bs0[BM * 32];
    __shared__ bf16 Bs1[BM * 32];

    const int NCB = D_DIM / 128;          // 8
    const int per = (NUM_RB * NCB) / 8;   // 136
    const int flat = blockIdx.x;
    const int sw = (flat & 7) * per + (flat >> 3);
    const int rb = sw / NCB, cb = sw % NCB;

    const int row0 = rb * BM;
    const int total = offsets[E_NUM];
    if (row0 >= total) return;
    int e = 0;
#pragma unroll
    for (int i = 1; i < E_NUM; ++i) e += (row0 >= offsets[i]) ? 1 : 0;

    const int tid = threadIdx.x;
    const int lane = tid & 63;
    const int w = tid >> 6;
    const int d0 = cb * 128;

    const int r0 = w * 16 + (lane >> 2);
    const int r1 = 64 + w * 16 + (lane >> 2);
    const int c16 = (lane & 3) ^ ((lane >> 3) & 3);
    const bf16* aP0 = hbuf + (size_t)(row0 + r0) * F_DIM + c16 * 8;
    const bf16* aP1 = hbuf + (size_t)(row0 + r1) * F_DIM + c16 * 8;
    const bf16* bP0 = W2t + ((size_t)e * D_DIM + d0 + r0) * F_DIM + c16 * 8;
    const bf16* bP1 = W2t + ((size_t)e * D_DIM + d0 + r1) * F_DIM + c16 * 8;

    const unsigned dO0 = __builtin_amdgcn_readfirstlane(w * 1024);
    const unsigned dO1 = __builtin_amdgcn_readfirstlane(4096 + w * 1024);

    const int wrow = (w >> 1) * 64, wcol = (w & 1) * 64;
    const int fr = lane & 15;
    const int fkk = 8 * ((lane >> 4) ^ ((lane >> 1) & 3));

    float4v acc[4][4];
#pragma unroll
    for (int m = 0; m < 4; ++m)
#pragma unroll
        for (int n = 0; n < 4; ++n)
#pragma unroll
            for (int r = 0; r < 4; ++r) acc[m][n][r] = 0.f;

    auto stage = [&](int kt, bf16* A, bf16* B) {
        const int ko = kt * 32;
        gl_lds16(aP0 + ko, (bf16*)((char*)A + dO0));
        gl_lds16(aP1 + ko, (bf16*)((char*)A + dO1));
        gl_lds16(bP0 + ko, (bf16*)((char*)B + dO0));
        gl_lds16(bP1 + ko, (bf16*)((char*)B + dO1));
    };

    const int NKT = F_DIM / 32;  // 128
    stage(0, As0, Bs0);
    stage(1, As1, Bs1);
    for (int kt = 0; kt < NKT - 2; kt += 2) {
        PH("vmcnt(4)", As0, Bs0, true, kt + 2);
        PH("vmcnt(4)", As1, Bs1, true, kt + 3);
    }
    PH("vmcnt(4)", As0, Bs0, false, 0);
    PH("vmcnt(0)", As1, Bs1, false, 0);

#pragma unroll
    for (int n = 0; n < 4; ++n) {
        const int gcol = d0 + wcol + n * 16 + fr;
        const float bias = b2[e * D_DIM + gcol];
#pragma unroll
        for (int m = 0; m < 4; ++m) {
#pragma unroll
            for (int r = 0; r < 4; ++r) {
                const int lrow = wrow + m * 16 + (lane >> 4) * 4 + r;
                const float g = gate_list[row0 + lrow];   // L2-hot, 128/block
                const float v = (acc[m][n][r] + bias) * g;
                y[(size_t)(row0 + lrow) * D_DIM + gcol] = __float2bfloat16(v);
            }
        }
    }
}

// ---- final reduce: out[t] = y[slot0(t)] + y[slot1(t)] (bf16 in, f32 out) ----
__global__ __launch_bounds__(256) void reduce_kernel(
    const bf16* __restrict__ y, const int* __restrict__ tok_slots,
    float* __restrict__ out) {
    const int t = blockIdx.x;
    const int s0 = tok_slots[2 * t], s1 = tok_slots[2 * t + 1];
    const ushort4* y0 = (const ushort4*)(y + (size_t)s0 * D_DIM);
    const ushort4* y1 = (const ushort4*)(y + (size_t)s1 * D_DIM);
    float4* o = (float4*)(out + (size_t)t * D_DIM);
    const int i = threadIdx.x;           // 256 threads x 4 bf16 = 1024 ✓
    const ushort4 a = y0[i], b = y1[i];
    const bf16* ap = (const bf16*)&a;
    const bf16* bp = (const bf16*)&b;
    float4 r;
    r.x = __bfloat162float(ap[0]) + __bfloat162float(bp[0]);
    r.y = __bfloat162float(ap[1]) + __bfloat162float(bp[1]);
    r.z = __bfloat162float(ap[2]) + __bfloat162float(bp[2]);
    r.w = __bfloat162float(ap[3]) + __bfloat162float(bp[3]);
    o[i] = r;
}

extern "C" void kernel_launch(void* const* d_in, const int* in_sizes, int n_in,
                              void* d_out, int out_size, void* d_ws, size_t ws_size,
                              hipStream_t stream) {
    const float* x = (const float*)d_in[0];
    const float* Wg = (const float*)d_in[1];
    const float* bg = (const float*)d_in[2];
    const float* W1 = (const float*)d_in[3];
    const float* b1 = (const float*)d_in[4];
    const float* W2 = (const float*)d_in[5];
    const float* b2 = (const float*)d_in[6];
    float* out = (float*)d_out;

    char* ws = (char*)d_ws;
    int* cursors = (int*)(ws + 32);     // 8 ints
    int* offsets = (int*)(ws + 64);     // 9 ints
    int* top_idx = (int*)(ws + 256);                     // T*2 ints
    float* top_gate = (float*)(ws + 256 + 65536);        // T*2 floats
    int* tok_list = (int*)(ws + 256 + 2 * 65536);        // MAX_ROWS ints
    float* gate_list = (float*)(ws + 256 + 2 * 65536 + 69632);
    int* tok_slots = (int*)(ws + 270592);                // T*2 ints = 64 KB
    size_t off = 270592 + 65536;                          // 336128
    bf16* xb = (bf16*)(ws + off);                        // 16.8 MB
    bf16* y = (bf16*)(ws + off);                         // 35 MB, aliases xb+W1t
    off += (size_t)T_TOK * D_DIM * 2;                    //  (dead after gemm1)
    bf16* W1t = (bf16*)(ws + off);
    off += (size_t)E_NUM * D_DIM * F_DIM * 2;
    bf16* W2t = (bf16*)(ws + off);
    off += (size_t)E_NUM * D_DIM * F_DIM * 2;
    bf16* hbuf = (bf16*)(ws + off);

    hipMemsetAsync(ws, 0, 64, stream);                       // cursors (+pad)
    hipMemsetAsync(tok_list, 0xFF, (size_t)MAX_ROWS * 4, stream);  // -1 sentinels

    prepA_kernel<<<8192 + T_TOK / 4, 256, 0, stream>>>(W1, W1t, x, Wg, bg,
                                                       top_idx, top_gate, xb);
    scatter_kernel<<<T_TOK / 256, 256, 0, stream>>>(top_idx, top_gate, offsets, cursors,
                                                    tok_list, gate_list, tok_slots);
    gemm1_w2t_kernel<<<G1_BLOCKS + 8192, 256, 0, stream>>>(xb, W1t, b1, tok_list,
                                                           offsets, hbuf, W2, W2t);
    gemm2_kernel<<<NUM_RB * (D_DIM / 128), 256, 0, stream>>>(hbuf, W2t, b2,
                                                             gate_list, offsets, y);
    reduce_kernel<<<T_TOK, 256, 0, stream>>>(y, tok_slots, out);
}

// Round 23
// 517.895 us; speedup vs baseline: 5.7599x; 1.0160x over previous
//
#include <hip/hip_runtime.h>
#include <hip/hip_bf16.h>

#define T_TOK 8192
#define D_DIM 1024
#define F_DIM 4096
#define E_NUM 8
#define BM 128
#define MAX_ROWS (2 * T_TOK + E_NUM * BM)   // 17408
#define NUM_RB (MAX_ROWS / BM)              // 136
#define G1_BLOCKS (NUM_RB * (F_DIM / 128))  // 4352

typedef __hip_bfloat16 bf16;
using bf16x8  = __attribute__((ext_vector_type(8))) __bf16;
using float4v = __attribute__((ext_vector_type(4))) float;
using f32x4   = __attribute__((ext_vector_type(4))) float;
using u16x4v  = __attribute__((ext_vector_type(4))) unsigned short;

// async global->LDS, 16B per lane; dest = uniform base + lane*16
__device__ inline void gl_lds16(const bf16* g, bf16* l) {
    __builtin_amdgcn_global_load_lds(
        (const __attribute__((address_space(1))) void*)g,
        (__attribute__((address_space(3))) void*)l, 16, 0, 0);
}

// R4 phase: counted vmcnt, pinned reads, 2 barriers, stage after 2nd barrier.
#define PH(WAITSTR, CA, CB, DOSTAGE, KST)                                      \
    do {                                                                       \
        asm volatile("s_waitcnt " WAITSTR ::: "memory");                       \
        __builtin_amdgcn_s_barrier();                                          \
        bf16x8 af[4], bfr[4];                                                  \
        _Pragma("unroll")                                                      \
        for (int m_ = 0; m_ < 4; ++m_)                                         \
            af[m_] = *(const bf16x8*)&(CA)[(wrow + m_ * 16 + fr) * 32 + fkk];  \
        _Pragma("unroll")                                                      \
        for (int n_ = 0; n_ < 4; ++n_)                                         \
            bfr[n_] = *(const bf16x8*)&(CB)[(wcol + n_ * 16 + fr) * 32 + fkk]; \
        asm volatile("s_waitcnt lgkmcnt(0)" ::: "memory");                     \
        __builtin_amdgcn_sched_barrier(0);                                     \
        __builtin_amdgcn_s_barrier();                                          \
        if (DOSTAGE) stage(KST, CA, CB);                                       \
        __builtin_amdgcn_s_setprio(1);                                         \
        _Pragma("unroll")                                                      \
        for (int m_ = 0; m_ < 4; ++m_)                                         \
            _Pragma("unroll")                                                  \
            for (int n_ = 0; n_ < 4; ++n_)                                     \
                acc[m_][n_] = __builtin_amdgcn_mfma_f32_16x16x32_bf16(         \
                    af[m_], bfr[n_], acc[m_][n_], 0, 0, 0);                    \
        __builtin_amdgcn_s_setprio(0);                                         \
    } while (0)

// shared transpose tile body (64x64 f32 -> bf16^T)
__device__ inline void transpose_tile(const float* s, bf16* d, int N, int M,
                                      int n0, int m0, float (*tile)[65]) {
    const int tx = threadIdx.x & 15, ty = threadIdx.x >> 4;
#pragma unroll
    for (int i = 0; i < 4; ++i) {
        const int r = ty + i * 16;
        const f32x4 v = *(const f32x4*)&s[(size_t)(m0 + r) * N + n0 + tx * 4];
        tile[r][tx * 4 + 0] = v[0];
        tile[r][tx * 4 + 1] = v[1];
        tile[r][tx * 4 + 2] = v[2];
        tile[r][tx * 4 + 3] = v[3];
    }
    __syncthreads();
#pragma unroll
    for (int i = 0; i < 4; ++i) {
        const int nc = ty + i * 16;
        u16x4v ov;
#pragma unroll
        for (int j = 0; j < 4; ++j) {
            bf16 b = __float2bfloat16(tile[tx * 4 + j][nc]);
            ov[j] = *(unsigned short*)&b;
        }
        *(u16x4v*)&d[(size_t)(n0 + nc) * M + m0 + tx * 4] = ov;
    }
}

// ---- fat dispatch A: W1-transpose (blocks 0..8191) + router+xcvt ----
__global__ __launch_bounds__(256) void prepA_kernel(
    const float* __restrict__ W1, bf16* __restrict__ W1t,
    const float* __restrict__ x, const float* __restrict__ Wg,
    const float* __restrict__ bg, int* __restrict__ top_idx,
    float* __restrict__ top_gate, bf16* __restrict__ xb) {
    __shared__ alignas(16) char pool[16640];
    const int bid = blockIdx.x;
    if (bid < 8192) {
        const int e = bid >> 10, rem = bid & 1023;
        const int n0 = (rem & 63) * 64, m0 = (rem >> 6) * 64;   // N=F, M=D
        transpose_tile(W1 + (size_t)e * D_DIM * F_DIM,
                       W1t + (size_t)e * D_DIM * F_DIM,
                       F_DIM, D_DIM, n0, m0, (float(*)[65])pool);
        return;
    }
    const int rbid = bid - 8192;
    const int lane = threadIdx.x & 63;
    const int t = rbid * 4 + (threadIdx.x >> 6);
    const float* xrow = x + (size_t)t * D_DIM;

    float acc[E_NUM];
#pragma unroll
    for (int e = 0; e < E_NUM; ++e) acc[e] = 0.f;
#pragma unroll
    for (int it = 0; it < D_DIM / 64; ++it) {
        const int d = it * 64 + lane;
        const float xv = xrow[d];
        const float4 w0 = *(const float4*)&Wg[d * 8];
        const float4 w1 = *(const float4*)&Wg[d * 8 + 4];
        acc[0] += xv * w0.x; acc[1] += xv * w0.y;
        acc[2] += xv * w0.z; acc[3] += xv * w0.w;
        acc[4] += xv * w1.x; acc[5] += xv * w1.y;
        acc[6] += xv * w1.z; acc[7] += xv * w1.w;
    }
#pragma unroll
    for (int off = 32; off > 0; off >>= 1) {
#pragma unroll
        for (int e = 0; e < E_NUM; ++e) acc[e] += __shfl_xor(acc[e], off, 64);
    }
    if (lane == 0) {
        float v[E_NUM];
#pragma unroll
        for (int e = 0; e < E_NUM; ++e) v[e] = acc[e] + bg[e];
        int i0 = 0;
#pragma unroll
        for (int e = 1; e < E_NUM; ++e)
            if (v[e] > v[i0]) i0 = e;
        int i1 = -1;
#pragma unroll
        for (int e = 0; e < E_NUM; ++e) {
            if (e == i0) continue;
            if (i1 < 0 || v[e] > v[i1]) i1 = e;
        }
        const float g0 = 1.f / (1.f + expf(v[i1] - v[i0]));
        top_idx[2 * t] = i0;
        top_idx[2 * t + 1] = i1;
        top_gate[2 * t] = g0;
        top_gate[2 * t + 1] = 1.f - g0;
    }
    const float4* xs = (const float4*)(x + (size_t)rbid * 4 * D_DIM);
    ushort4* xd = (ushort4*)(xb + (size_t)rbid * 4 * D_DIM);
    for (int i = threadIdx.x; i < D_DIM; i += 256) {
        float4 v = xs[i];
        bf16 tmp[4];
        tmp[0] = __float2bfloat16(v.x);
        tmp[1] = __float2bfloat16(v.y);
        tmp[2] = __float2bfloat16(v.z);
        tmp[3] = __float2bfloat16(v.w);
        xd[i] = *(const ushort4*)tmp;
    }
}

// ---- scatter with inline recount+offsets ----
__global__ __launch_bounds__(256) void scatter_kernel(
    const int* __restrict__ top_idx, const float* __restrict__ top_gate,
    int* __restrict__ offsets, int* __restrict__ cursors,
    int* __restrict__ tok_list, float* __restrict__ gate_list,
    int* __restrict__ tok_slots) {
    __shared__ int whist[4][E_NUM];
    __shared__ int offs_s[E_NUM + 1];
    __shared__ int lhist[E_NUM];
    __shared__ int lbase[E_NUM];

    int cnt[E_NUM];
#pragma unroll
    for (int e = 0; e < E_NUM; ++e) cnt[e] = 0;
    for (int i = threadIdx.x; i < 2 * T_TOK; i += 256) {
        const int idx = top_idx[i];
#pragma unroll
        for (int e = 0; e < E_NUM; ++e) cnt[e] += (idx == e) ? 1 : 0;
    }
#pragma unroll
    for (int off = 32; off > 0; off >>= 1) {
#pragma unroll
        for (int e = 0; e < E_NUM; ++e) cnt[e] += __shfl_xor(cnt[e], off, 64);
    }
    const int lane = threadIdx.x & 63, w = threadIdx.x >> 6;
    if (lane == 0) {
#pragma unroll
        for (int e = 0; e < E_NUM; ++e) whist[w][e] = cnt[e];
    }
    if (threadIdx.x < E_NUM) lhist[threadIdx.x] = 0;
    __syncthreads();
    if (threadIdx.x == 0) {
        int o = 0;
#pragma unroll
        for (int e = 0; e < E_NUM; ++e) {
            const int c = whist[0][e] + whist[1][e] + whist[2][e] + whist[3][e];
            offs_s[e] = o;
            o += (c + BM - 1) / BM * BM;
        }
        offs_s[E_NUM] = o;
    }
    __syncthreads();
    if (blockIdx.x == 0 && threadIdx.x < E_NUM + 1)
        offsets[threadIdx.x] = offs_s[threadIdx.x];

    const int t = blockIdx.x * 256 + threadIdx.x;
    int e0 = top_idx[2 * t], e1 = top_idx[2 * t + 1];
    int p0 = atomicAdd(&lhist[e0], 1);
    int p1 = atomicAdd(&lhist[e1], 1);
    __syncthreads();
    if (threadIdx.x < E_NUM)
        lbase[threadIdx.x] = atomicAdd(&cursors[threadIdx.x], lhist[threadIdx.x]);
    __syncthreads();

    const float g0 = top_gate[2 * t], g1 = top_gate[2 * t + 1];
    const int s0 = offs_s[e0] + lbase[e0] + p0;
    const int s1 = offs_s[e1] + lbase[e1] + p1;
    tok_list[s0] = t;
    gate_list[s0] = g0;
    tok_list[s1] = t;
    gate_list[s1] = g1;
    tok_slots[2 * t] = s0;
    tok_slots[2 * t + 1] = s1;
}

// ---- fat dispatch B: GEMM1 (exact R4) + W2-transpose ----
__global__ __launch_bounds__(256, 4) void gemm1_w2t_kernel(
    const bf16* __restrict__ xb, const bf16* __restrict__ W1t,
    const float* __restrict__ b1, const int* __restrict__ tok_list,
    const int* __restrict__ offsets, bf16* __restrict__ hbuf,
    const float* __restrict__ W2, bf16* __restrict__ W2t) {
    __shared__ alignas(16) char pool[33280];
    if (blockIdx.x >= G1_BLOCKS) {
        const int f2 = blockIdx.x - G1_BLOCKS;
        const int e = f2 >> 10, rem = f2 & 1023;
        const int n0 = (rem & 15) * 64, m0 = (rem >> 4) * 64;   // N=D, M=F
        transpose_tile(W2 + (size_t)e * D_DIM * F_DIM,
                       W2t + (size_t)e * D_DIM * F_DIM,
                       D_DIM, F_DIM, n0, m0, (float(*)[65])pool);
        return;
    }
    bf16* As0 = (bf16*)pool;
    bf16* As1 = (bf16*)(pool + 8192);
    bf16* Bs0 = (bf16*)(pool + 16384);
    bf16* Bs1 = (bf16*)(pool + 24576);
    int* toks = (int*)(pool + 32768);

    const int NCB = F_DIM / 128;          // 32
    const int per = (NUM_RB * NCB) / 8;   // 544
    const int flat = blockIdx.x;
    const int sw = (flat & 7) * per + (flat >> 3);
    const int rb = sw / NCB, cb = sw % NCB;

    const int row0 = rb * BM;
    const int total = offsets[E_NUM];
    if (row0 >= total) return;
    int e = 0;
#pragma unroll
    for (int i = 1; i < E_NUM; ++i) e += (row0 >= offsets[i]) ? 1 : 0;

    const int tid = threadIdx.x;
    if (tid < BM) toks[tid] = tok_list[row0 + tid];
    __syncthreads();   // full drain: vmcnt henceforth counts only stage loads

    const int lane = tid & 63;
    const int w = tid >> 6;
    const int f0 = cb * 128;

    const int r0 = w * 16 + (lane >> 2);
    const int r1 = 64 + w * 16 + (lane >> 2);
    const int c16 = (lane & 3) ^ ((lane >> 3) & 3);
    int t0 = toks[r0]; if (t0 < 0) t0 = 0;
    int t1 = toks[r1]; if (t1 < 0) t1 = 0;
    const bf16* aP0 = xb + (size_t)t0 * D_DIM + c16 * 8;
    const bf16* aP1 = xb + (size_t)t1 * D_DIM + c16 * 8;
    const bf16* bP0 = W1t + ((size_t)e * F_DIM + f0 + r0) * D_DIM + c16 * 8;
    const bf16* bP1 = W1t + ((size_t)e * F_DIM + f0 + r1) * D_DIM + c16 * 8;

    const unsigned dO0 = __builtin_amdgcn_readfirstlane(w * 1024);
    const unsigned dO1 = __builtin_amdgcn_readfirstlane(4096 + w * 1024);

    const int wrow = (w >> 1) * 64, wcol = (w & 1) * 64;
    const int fr = lane & 15;
    const int fkk = 8 * ((lane >> 4) ^ ((lane >> 1) & 3));

    float4v acc[4][4];
#pragma unroll
    for (int m = 0; m < 4; ++m)
#pragma unroll
        for (int n = 0; n < 4; ++n)
#pragma unroll
            for (int r = 0; r < 4; ++r) acc[m][n][r] = 0.f;

    auto stage = [&](int kt, bf16* A, bf16* B) {
        const int ko = kt * 32;
        gl_lds16(aP0 + ko, (bf16*)((char*)A + dO0));
        gl_lds16(aP1 + ko, (bf16*)((char*)A + dO1));
        gl_lds16(bP0 + ko, (bf16*)((char*)B + dO0));
        gl_lds16(bP1 + ko, (bf16*)((char*)B + dO1));
    };

    const int NKT = D_DIM / 32;  // 32
    stage(0, As0, Bs0);
    stage(1, As1, Bs1);
    for (int kt = 0; kt < NKT - 2; kt += 2) {
        PH("vmcnt(4)", As0, Bs0, true, kt + 2);
        PH("vmcnt(4)", As1, Bs1, true, kt + 3);
    }
    PH("vmcnt(4)", As0, Bs0, false, 0);
    PH("vmcnt(0)", As1, Bs1, false, 0);

#pragma unroll
    for (int n = 0; n < 4; ++n) {
        const int gcol = f0 + wcol + n * 16 + fr;
        const float bias = b1[e * F_DIM + gcol];
#pragma unroll
        for (int m = 0; m < 4; ++m) {
#pragma unroll
            for (int r = 0; r < 4; ++r) {
                const int grow = row0 + wrow + m * 16 + (lane >> 4) * 4 + r;
                float v = acc[m][n][r] + bias;
                v = fmaxf(v, 0.f);
                hbuf[(size_t)grow * F_DIM + gcol] = __float2bfloat16(v);
            }
        }
    }
}

// ---------------- GEMM2 (exact R4 loop): y[slot] = gate*(h@W2 + b2), bf16 ----
__global__ __launch_bounds__(256, 4) void gemm2_kernel(
    const bf16* __restrict__ hbuf, const bf16* __restrict__ W2t,
    const float* __restrict__ b2, const int* __restrict__ tok_list,
    const float* __restrict__ gate_list, const int* __restrict__ offsets,
    bf16* __restrict__ y) {
    __shared__ bf16 As0[BM * 32];
    __shared__ bf16 As1[BM * 32];
    __shared__ bf16 Bs0[BM * 32];
    __shared__ bf16 Bs1[BM * 32];
    __shared__ float gates_s[BM];

    const int NCB = D_DIM / 128;          // 8
    const int per = (NUM_RB * NCB) / 8;   // 136
    const int flat = blockIdx.x;
    const int sw = (flat & 7) * per + (flat >> 3);
    const int rb = sw / NCB, cb = sw % NCB;

    const int row0 = rb * BM;
    const int total = offsets[E_NUM];
    if (row0 >= total) return;
    int e = 0;
#pragma unroll
    for (int i = 1; i < E_NUM; ++i) e += (row0 >= offsets[i]) ? 1 : 0;

    const int tid = threadIdx.x;
    if (tid < BM) {
        int t = tok_list[row0 + tid];
        gates_s[tid] = (t >= 0) ? gate_list[row0 + tid] : 0.f;
    }
    __syncthreads();

    const int lane = tid & 63;
    const int w = tid >> 6;
    const int d0 = cb * 128;

    const int r0 = w * 16 + (lane >> 2);
    const int r1 = 64 + w * 16 + (lane >> 2);
    const int c16 = (lane & 3) ^ ((lane >> 3) & 3);
    const bf16* aP0 = hbuf + (size_t)(row0 + r0) * F_DIM + c16 * 8;
    const bf16* aP1 = hbuf + (size_t)(row0 + r1) * F_DIM + c16 * 8;
    const bf16* bP0 = W2t + ((size_t)e * D_DIM + d0 + r0) * F_DIM + c16 * 8;
    const bf16* bP1 = W2t + ((size_t)e * D_DIM + d0 + r1) * F_DIM + c16 * 8;

    const unsigned dO0 = __builtin_amdgcn_readfirstlane(w * 1024);
    const unsigned dO1 = __builtin_amdgcn_readfirstlane(4096 + w * 1024);

    const int wrow = (w >> 1) * 64, wcol = (w & 1) * 64;
    const int fr = lane & 15;
    const int fkk = 8 * ((lane >> 4) ^ ((lane >> 1) & 3));

    float4v acc[4][4];
#pragma unroll
    for (int m = 0; m < 4; ++m)
#pragma unroll
        for (int n = 0; n < 4; ++n)
#pragma unroll
            for (int r = 0; r < 4; ++r) acc[m][n][r] = 0.f;

    auto stage = [&](int kt, bf16* A, bf16* B) {
        const int ko = kt * 32;
        gl_lds16(aP0 + ko, (bf16*)((char*)A + dO0));
        gl_lds16(aP1 + ko, (bf16*)((char*)A + dO1));
        gl_lds16(bP0 + ko, (bf16*)((char*)B + dO0));
        gl_lds16(bP1 + ko, (bf16*)((char*)B + dO1));
    };

    const int NKT = F_DIM / 32;  // 128
    stage(0, As0, Bs0);
    stage(1, As1, Bs1);
    for (int kt = 0; kt < NKT - 2; kt += 2) {
        PH("vmcnt(4)", As0, Bs0, true, kt + 2);
        PH("vmcnt(4)", As1, Bs1, true, kt + 3);
    }
    PH("vmcnt(4)", As0, Bs0, false, 0);
    PH("vmcnt(0)", As1, Bs1, false, 0);

#pragma unroll
    for (int n = 0; n < 4; ++n) {
        const int gcol = d0 + wcol + n * 16 + fr;
        const float bias = b2[e * D_DIM + gcol];
#pragma unroll
        for (int m = 0; m < 4; ++m) {
#pragma unroll
            for (int r = 0; r < 4; ++r) {
                const int lrow = wrow + m * 16 + (lane >> 4) * 4 + r;
                const float v = (acc[m][n][r] + bias) * gates_s[lrow];
                y[(size_t)(row0 + lrow) * D_DIM + gcol] = __float2bfloat16(v);
            }
        }
    }
}

// ---- final reduce: out[t] = y[slot0(t)] + y[slot1(t)] (bf16 in, f32 out) ----
__global__ __launch_bounds__(256) void reduce_kernel(
    const bf16* __restrict__ y, const int* __restrict__ tok_slots,
    float* __restrict__ out) {
    const int t = blockIdx.x;
    const int s0 = tok_slots[2 * t], s1 = tok_slots[2 * t + 1];
    const ushort4* y0 = (const ushort4*)(y + (size_t)s0 * D_DIM);
    const ushort4* y1 = (const ushort4*)(y + (size_t)s1 * D_DIM);
    float4* o = (float4*)(out + (size_t)t * D_DIM);
    const int i = threadIdx.x;           // 256 threads x 4 bf16 = 1024 ✓
    const ushort4 a = y0[i], b = y1[i];
    const bf16* ap = (const bf16*)&a;
    const bf16* bp = (const bf16*)&b;
    float4 r;
    r.x = __bfloat162float(ap[0]) + __bfloat162float(bp[0]);
    r.y = __bfloat162float(ap[1]) + __bfloat162float(bp[1]);
    r.z = __bfloat162float(ap[2]) + __bfloat162float(bp[2]);
    r.w = __bfloat162float(ap[3]) + __bfloat162float(bp[3]);
    o[i] = r;
}

extern "C" void kernel_launch(void* const* d_in, const int* in_sizes, int n_in,
                              void* d_out, int out_size, void* d_ws, size_t ws_size,
                              hipStream_t stream) {
    const float* x = (const float*)d_in[0];
    const float* Wg = (const float*)d_in[1];
    const float* bg = (const float*)d_in[2];
    const float* W1 = (const float*)d_in[3];
    const float* b1 = (const float*)d_in[4];
    const float* W2 = (const float*)d_in[5];
    const float* b2 = (const float*)d_in[6];
    float* out = (float*)d_out;

    char* ws = (char*)d_ws;
    int* cursors = (int*)(ws + 32);     // 8 ints
    int* offsets = (int*)(ws + 64);     // 9 ints
    int* top_idx = (int*)(ws + 256);                     // T*2 ints
    float* top_gate = (float*)(ws + 256 + 65536);        // T*2 floats
    int* tok_list = (int*)(ws + 256 + 2 * 65536);        // MAX_ROWS ints
    float* gate_list = (float*)(ws + 256 + 2 * 65536 + 69632);
    int* tok_slots = (int*)(ws + 270592);                // T*2 ints = 64 KB
    size_t off = 270592 + 65536;                          // 336128
    bf16* xb = (bf16*)(ws + off);                        // 16.8 MB
    bf16* y = (bf16*)(ws + off);                         // 35 MB, aliases xb+W1t
    off += (size_t)T_TOK * D_DIM * 2;                    //  (dead after gemm1)
    bf16* W1t = (bf16*)(ws + off);
    off += (size_t)E_NUM * D_DIM * F_DIM * 2;
    bf16* W2t = (bf16*)(ws + off);
    off += (size_t)E_NUM * D_DIM * F_DIM * 2;
    bf16* hbuf = (bf16*)(ws + off);

    hipMemsetAsync(ws, 0, 64, stream);                       // cursors (+pad)
    hipMemsetAsync(tok_list, 0xFF, (size_t)MAX_ROWS * 4, stream);  // -1 sentinels

    prepA_kernel<<<8192 + T_TOK / 4, 256, 0, stream>>>(W1, W1t, x, Wg, bg,
                                                       top_idx, top_gate, xb);
    scatter_kernel<<<T_TOK / 256, 256, 0, stream>>>(top_idx, top_gate, offsets, cursors,
                                                    tok_list, gate_list, tok_slots);
    gemm1_w2t_kernel<<<G1_BLOCKS + 8192, 256, 0, stream>>>(xb, W1t, b1, tok_list,
                                                           offsets, hbuf, W2, W2t);
    gemm2_kernel<<<NUM_RB * (D_DIM / 128), 256, 0, stream>>>(hbuf, W2t, b2, tok_list,
                                                             gate_list, offsets, y);
    reduce_kernel<<<T_TOK, 256, 0, stream>>>(y, tok_slots, out);
}